// Round 10
// baseline (284.436 us; speedup 1.0000x reference)
//
#include <hip/hip_runtime.h>

// DNNF fused pipeline for MI355X (gfx950). R10: A-operand direct global->reg
// with REGISTER double-buffer (next tile's A loaded one full iter ahead),
// B staged via the proven R4 LDS double-buffer. Staged DMA bytes drop
// 1.19 GB -> 0.73 GB; cross-round audit shows every variant is bound by the
// LDS-DMA rate (~8.2 TB/s at 2 blocks/CU), so bytes are the lever.
// CRITICAL vs R6's failed direct-A: keep R4 grid (x=n fastest) so the 58
// consecutive blocks share one A tile -> A reads are L2-hot.
// Epilogue = R4's 2-phase slit (measured 0 bank conflicts).

#define BATCH 8192
#define IDIM 512
#define NFORM 256
#define NLIT 10752
#define WT_ROWS 11136  // NLIT + 256 mu + 128 zero pad; /192 = 58 tiles

#define BM 128
#define BN 192
#define BK 64
#define BUFB 24576  // one LDS B buffer: 192 rows x 64 bf16
#define SLITP 196   // slit row stride (floats)

typedef __bf16 bf16x8 __attribute__((ext_vector_type(8)));
typedef float f32x4 __attribute__((ext_vector_type(4)));
typedef unsigned short u16;
typedef unsigned int u32;

__device__ __forceinline__ u16 f2bf(float f) {
  u32 u = __float_as_uint(f);
  u = (u + 0x7fffu + ((u >> 16) & 1u)) >> 16;  // RNE
  return (u16)u;
}

__device__ __forceinline__ float fast_tanh(float x) {
  float e = __expf(2.0f * x);
  return 1.0f - 2.0f * __builtin_amdgcn_rcpf(e + 1.0f);
}

__device__ __forceinline__ void async_cp16(const void* g, void* l) {
  __builtin_amdgcn_global_load_lds(
      (const u32 __attribute__((address_space(1)))*)g,
      (u32 __attribute__((address_space(3)))*)l, 16, 0, 0);
}

// ---------------- fused prep (one dispatch) ----------------

#define PREPX_BLKS 2048
#define PREPW_BLKS 1344  // 168 l-tiles x 8 k-tiles

__global__ __launch_bounds__(256) void prep_all(
    const float* __restrict__ x, const float* __restrict__ W,
    const float* __restrict__ M, const float* __restrict__ mu,
    u16* __restrict__ xb, u16* __restrict__ wt, float* __restrict__ xsq,
    float* __restrict__ musq, float* __restrict__ form_sum) {
  __shared__ float lds[64 * 65];  // 16.6 KB; also reused as red[256]
  const int blk = blockIdx.x, tid = threadIdx.x;

  if (blk < PREPX_BLKS) {
    ((uint4*)form_sum)[blk * 256 + tid] = make_uint4(0, 0, 0, 0);
    int wave = tid >> 6, lane = tid & 63;
    int row = blk * 4 + wave;
    const float4* px = (const float4*)(x + (size_t)row * IDIM);
    float4 a = px[lane * 2], b = px[lane * 2 + 1];
    uint4 pk;
    pk.x = (u32)f2bf(a.x) | ((u32)f2bf(a.y) << 16);
    pk.y = (u32)f2bf(a.z) | ((u32)f2bf(a.w) << 16);
    pk.z = (u32)f2bf(b.x) | ((u32)f2bf(b.y) << 16);
    pk.w = (u32)f2bf(b.z) | ((u32)f2bf(b.w) << 16);
    ((uint4*)(xb + (size_t)row * IDIM))[lane] = pk;
    float s = a.x * a.x + a.y * a.y + a.z * a.z + a.w * a.w +
              b.x * b.x + b.y * b.y + b.z * b.z + b.w * b.w;
#pragma unroll
    for (int o = 32; o > 0; o >>= 1) s += __shfl_down(s, o);
    if (lane == 0) xsq[row] = s;
  } else if (blk < PREPX_BLKS + PREPW_BLKS) {
    int b = blk - PREPX_BLKS;
    int l0 = (b % 168) * 64, k0 = (b / 168) * 64;
#pragma unroll
    for (int j = 0; j < 4; ++j) {
      int idx = tid + j * 256;
      int kk = idx >> 4, l4 = idx & 15;
      size_t g = (size_t)(k0 + kk) * NLIT + l0 + l4 * 4;
      float4 w4 = *(const float4*)(W + g);
      float4 m4 = *(const float4*)(M + g);
      lds[kk * 65 + l4 * 4 + 0] = w4.x * m4.x;
      lds[kk * 65 + l4 * 4 + 1] = w4.y * m4.y;
      lds[kk * 65 + l4 * 4 + 2] = w4.z * m4.z;
      lds[kk * 65 + l4 * 4 + 3] = w4.w * m4.w;
    }
    __syncthreads();
    int l = tid >> 2, kq = tid & 3;
    u32 pk[8];
#pragma unroll
    for (int t = 0; t < 8; ++t) {
      u16 lo = f2bf(lds[(kq * 16 + 2 * t) * 65 + l]);
      u16 hi = f2bf(lds[(kq * 16 + 2 * t + 1) * 65 + l]);
      pk[t] = (u32)lo | ((u32)hi << 16);
    }
    u32* dst = (u32*)(wt + (size_t)(l0 + l) * IDIM + k0 + kq * 16);
    ((uint4*)dst)[0] = make_uint4(pk[0], pk[1], pk[2], pk[3]);
    ((uint4*)dst)[1] = make_uint4(pk[4], pk[5], pk[6], pk[7]);
  } else {
    int b = blk - PREPX_BLKS - PREPW_BLKS;
    if (b < 256) {
      float s = 0.f;
#pragma unroll
      for (int j = tid; j < IDIM; j += 256) {
        float v = mu[(size_t)b * IDIM + j];
        wt[(size_t)(NLIT + b) * IDIM + j] = f2bf(v);
        s += v * v;
      }
      float* red = lds;
      red[tid] = s;
      __syncthreads();
      for (int sh = 128; sh > 0; sh >>= 1) {
        if (tid < sh) red[tid] += red[tid + sh];
        __syncthreads();
      }
      if (tid == 0) musq[b] = red[0];
    } else {
      int row = NLIT + 256 + (b - 256);  // 11008..11135
      for (int j = tid; j < IDIM; j += 256) wt[(size_t)row * IDIM + j] = 0;
    }
  }
}

// ---------------- main fused GEMM ----------------
// A: direct global->reg, register-double-buffered one K-tile ahead.
//    A-frag layout == xb memory layout (lane cn reads row m0+wm*64+mf*16+cn,
//    8 contiguous K at q*8 + ks*32). L2-hot under the x=n grid.
// B: LDS double-buffer, XOR swizzle (kg_phys = kg ^ (row&7)).
// Iter kt: issue B-DMA(kt+1)[6] then A-loads(kt+1)[8]; vmcnt(14) retires
// exactly B(kt)+A(kt); barrier; ds_read B + 48 MFMA; lgkm(0)+barrier.

__global__ __launch_bounds__(256, 2) void dnnf_gemm(
    const u16* __restrict__ xb, const u16* __restrict__ wt,
    const float* __restrict__ bias, float* __restrict__ form_sum,
    float* __restrict__ dotbuf) {
  __shared__ __align__(16) char smraw[64 * SLITP * 4];  // 50176 B
  float* slit = (float*)smraw;  // epilogue view 64 x SLITP

  const int tid = threadIdx.x;
  const int wave = tid >> 6, lane = tid & 63;
  const int wm = wave & 1, wn = wave >> 1;
  // R4 grid: x = n (58, fastest -> consecutive blocks share A tile), y = m
  const int m0 = blockIdx.y * BM, n0 = blockIdx.x * BN;
  const int q = lane >> 4, cn = lane & 15;

  // B staging: chunk c = tid + i*256 (i<6), r = c>>3, kg = (c&7) ^ (r&7)
  const int kg8 = ((tid & 7) ^ ((tid >> 3) & 7)) * 8;
  const u16* pb = wt + (size_t)(n0 + (tid >> 3)) * IDIM + kg8;
  const int dB = tid * 16;  // + i*4096, i<6

  // A direct-load base: row = m0 + wm*64 + cn (+ mf*16), K-offset q*8
  const u16* pA = xb + (size_t)(m0 + wm * 64 + cn) * IDIM + q * 8;

  const int kg0_16 = ((q ^ (cn & 7)) << 4);
  int offB[6];
#pragma unroll
  for (int nf = 0; nf < 6; ++nf)
    offB[nf] = (wn * 96 + nf * 16 + cn) * 128 + kg0_16;

  f32x4 acc[4][6];
#pragma unroll
  for (int a = 0; a < 4; ++a)
#pragma unroll
    for (int b = 0; b < 6; ++b) acc[a][b] = (f32x4){0.f, 0.f, 0.f, 0.f};

  // prologue: B(0) -> buf0, A(0) -> regs (parity 0)
  bf16x8 af[2][2][4];  // [kt parity][ks][mf]
#pragma unroll
  for (int i = 0; i < 6; ++i)
    async_cp16(pb + (size_t)i * 32 * IDIM, smraw + dB + i * 4096);
#pragma unroll
  for (int ks = 0; ks < 2; ++ks)
#pragma unroll
    for (int mf = 0; mf < 4; ++mf)
      af[0][ks][mf] =
          *(const bf16x8*)(pA + (size_t)mf * 16 * IDIM + ks * 32);

#pragma unroll
  for (int kt = 0; kt < 8; ++kt) {
    const char* bufc = smraw + (kt & 1) * BUFB;
    if (kt < 7) {
      char* bufn = smraw + ((kt + 1) & 1) * BUFB;
#pragma unroll
      for (int i = 0; i < 6; ++i)
        async_cp16(pb + (size_t)(kt + 1) * BK + (size_t)i * 32 * IDIM,
                   bufn + dB + i * 4096);
#pragma unroll
      for (int ks = 0; ks < 2; ++ks)
#pragma unroll
        for (int mf = 0; mf < 4; ++mf)
          af[(kt + 1) & 1][ks][mf] =
              *(const bf16x8*)(pA + (size_t)mf * 16 * IDIM +
                               (kt + 1) * BK + ks * 32);
      // retire exactly B(kt)[6]+A(kt)[8]; keep B(kt+1)+A(kt+1)=14 in flight
      asm volatile("s_waitcnt vmcnt(14)\n\ts_barrier" ::: "memory");
    } else {
      asm volatile("s_waitcnt vmcnt(0)\n\ts_barrier" ::: "memory");
    }
#pragma unroll
    for (int ks = 0; ks < 2; ++ks) {
      const int x64 = ks ? 64 : 0;
      bf16x8 bfr[6];
#pragma unroll
      for (int nf = 0; nf < 6; ++nf)
        bfr[nf] = *(const bf16x8*)(bufc + (offB[nf] ^ x64));
#pragma unroll
      for (int mf = 0; mf < 4; ++mf)
#pragma unroll
        for (int nf = 0; nf < 6; ++nf)
          acc[mf][nf] = __builtin_amdgcn_mfma_f32_16x16x32_bf16(
              af[kt & 1][ks][mf], bfr[nf], acc[mf][nf], 0, 0, 0);
    }
    if (kt < 7)
      asm volatile("s_waitcnt lgkmcnt(0)\n\ts_barrier" ::: "memory");
  }
  __syncthreads();  // full drain before LDS reuse as slit

  if (n0 < NLIT) {
    float bv[6];
#pragma unroll
    for (int nf = 0; nf < 6; ++nf) bv[nf] = bias[n0 + wn * 96 + nf * 16 + cn];

    // R4 epilogue: two phases of 64 rows, one 64 x SLITP slit tile
#pragma unroll
    for (int ph = 0; ph < 2; ++ph) {
      if (ph) __syncthreads();  // phase-0 reads done before overwrite
      if (wm == ph) {
#pragma unroll
        for (int nf = 0; nf < 6; ++nf) {
          int col = wn * 96 + nf * 16 + cn;
#pragma unroll
          for (int mf = 0; mf < 4; ++mf)
#pragma unroll
            for (int reg = 0; reg < 4; ++reg) {
              int lr = mf * 16 + q * 4 + reg;
              slit[lr * SLITP + col] = fast_tanh(acc[mf][nf][reg] + bv[nf]);
            }
        }
      }
      __syncthreads();

      int r = tid >> 2, sub = tid & 3;  // 64 rows x 4 threads (48 lits each)
      const float* lrow = slit + r * SLITP + sub * 48;
      int c0 = ((n0 + sub * 48) / 12) * 3;
      size_t grow = (size_t)(m0 + ph * 64 + r) * NFORM;
      float run = 0.f;
      int fprev = -1;
#pragma unroll
      for (int tr = 0; tr < 4; ++tr) {
        const float* p = lrow + tr * 12;
        float s2 = p[0] + p[1];
        float s4 = p[2] + p[3] + p[4] + p[5];
        float s6 = p[6] + p[7] + p[8] + p[9] + p[10] + p[11];
        float v = fast_tanh(s2 - 0.5f) + fast_tanh(s4 - 2.5f) +
                  fast_tanh(s6 - 4.5f);
        int c = c0 + tr * 3;
        int f = (c < 384)    ? (c / 6)
                : (c < 960)  ? 64 + (c - 384) / 9
                : (c < 1728) ? 128 + (c - 960) / 12
                             : 192 + (c - 1728) / 15;
        if (f != fprev) {
          if (fprev >= 0) atomicAdd(form_sum + grow + fprev, run);
          fprev = f;
          run = 0.f;
        }
        run += v;
      }
      atomicAdd(form_sum + grow + fprev, run);
    }
  } else {
    // mu tiles: store raw x.mu dots
#pragma unroll
    for (int nf = 0; nf < 6; ++nf) {
      int col = n0 - NLIT + wn * 96 + nf * 16 + cn;
      if (col < NFORM) {
#pragma unroll
        for (int mf = 0; mf < 4; ++mf)
#pragma unroll
          for (int reg = 0; reg < 4; ++reg) {
            int row = wm * 64 + mf * 16 + q * 4 + reg;
            dotbuf[(size_t)(m0 + row) * NFORM + col] = acc[mf][nf][reg];
          }
      }
    }
  }
}

// ---------------- finale: RBF softmax * dnnf (wave-per-row) ----------------

__global__ __launch_bounds__(256) void finale(
    const float* __restrict__ form_sum, const float* __restrict__ dotbuf,
    const float* __restrict__ xsq, const float* __restrict__ musq,
    const float* __restrict__ sigma, float* __restrict__ out) {
  int wave = threadIdx.x >> 6, lane = threadIdx.x & 63;
  int r = blockIdx.x * 4 + wave;
  size_t base = (size_t)r * NFORM;
  float xs = xsq[r];
  float e[4], s = 0.f;
#pragma unroll
  for (int j = 0; j < 4; ++j) {
    int f = j * 64 + lane;
    float sq = xs - 2.0f * dotbuf[base + f] + musq[f];
    float sg = sigma[f];
    float p = __expf(-0.5f * sq / (sg * sg));
    e[j] = __expf(2.0f * p);  // TEMPERATURE=2; values in [1, e^2]
    s += e[j];
  }
#pragma unroll
  for (int o = 32; o > 0; o >>= 1) s += __shfl_xor(s, o);
  float inv = __builtin_amdgcn_rcpf(s);
#pragma unroll
  for (int j = 0; j < 4; ++j) {
    int f = j * 64 + lane;
    float dn = fast_tanh(form_sum[base + f] + (float)(6 + 3 * j) - 1.5f);
    out[base + f] = dn * e[j] * inv;
  }
}

// ---------------- launch ----------------

extern "C" void kernel_launch(void* const* d_in, const int* in_sizes, int n_in,
                              void* d_out, int out_size, void* d_ws,
                              size_t ws_size, hipStream_t stream) {
  const float* x = (const float*)d_in[0];
  const float* W = (const float*)d_in[1];
  const float* M = (const float*)d_in[2];
  const float* bias = (const float*)d_in[3];
  const float* mu = (const float*)d_in[4];
  const float* sigma = (const float*)d_in[5];
  float* out = (float*)d_out;

  float* form_sum = (float*)d_ws;                       // 8 MB
  float* dotbuf = form_sum + (size_t)BATCH * NFORM;     // 8 MB
  u16* xb = (u16*)(dotbuf + (size_t)BATCH * NFORM);     // 8 MB
  u16* wt = xb + (size_t)BATCH * IDIM;                  // 11.4 MB
  float* xsq = (float*)(wt + (size_t)WT_ROWS * IDIM);   // 32 KB
  float* musq = xsq + BATCH;                            // 1 KB

  prep_all<<<PREPX_BLKS + PREPW_BLKS + 384, 256, 0, stream>>>(
      x, W, M, mu, xb, wt, xsq, musq, form_sum);
  // R4 grid: x = n (58), y = m (64)
  dnnf_gemm<<<dim3(WT_ROWS / BN, BATCH / BM), 256, 0, stream>>>(xb, wt, bias,
                                                                form_sum, dotbuf);
  finale<<<BATCH / 4, 256, 0, stream>>>(form_sum, dotbuf, xsq, musq, sigma, out);
}